// Round 4
// baseline (235.254 us; speedup 1.0000x reference)
//
#include <hip/hip_runtime.h>

// Problem constants (from reference setup_inputs)
#define Bn 256
#define En 8
#define Vn 32000
#define Ln 128
#define BEn (Bn * En)        // 2048
#define END_TOK 2

// d_out layout (all values stored as float32, outputs concatenated in return order)
#define OFF_CUR   0                         // cur_input  [B*E]
#define OFF_TOPP  (BEn)                     // top_p      [B,E]
#define OFF_OUTS  (2 * BEn)                 // outs_new   [L+1,B,E]
#define OFF_ENDED (2 * BEn + (Ln + 1) * BEn) // ended_new [B,E]
#define OFF_BEAM  (3 * BEn + (Ln + 1) * BEn) // topk_beam [B,E]

#define NEG_INF (-__builtin_inff())
#define IDX_SENTINEL 0x7fffffff

// Butterfly arg-max over 64 lanes under total order (val desc, idx asc).
// All real candidates have unique idx, so the winner (v, ix, ln) is
// consistent across all lanes (sentinels tie only with each other and
// always lose to any real candidate).
__device__ __forceinline__ void wave_argmax(float& v, int& ix, int& ln) {
#pragma unroll
    for (int off = 32; off > 0; off >>= 1) {
        float v2 = __shfl_xor(v, off, 64);
        int   i2 = __shfl_xor(ix, off, 64);
        int   l2 = __shfl_xor(ln, off, 64);
        bool take = (v2 > v) || (v2 == v && i2 < ix);
        v  = take ? v2 : v;
        ix = take ? i2 : ix;
        ln = take ? l2 : ln;
    }
}

// Kernel 1: per-(b,e) segment top-8 of total[v] = proba[be] + cp[be][v].
// grid = BEn blocks x 256 threads. Emits 8 (val, global_idx=e*V+v) candidates
// per segment to ws. All top-8 state is in registers (compile-time indexing).
__global__ __launch_bounds__(256) void k_seg_topk(
        const float* __restrict__ cp, const float* __restrict__ proba,
        const int* __restrict__ ended,
        float* __restrict__ cand_v, int* __restrict__ cand_i) {
    const int be = blockIdx.x;
    const int e  = be & (En - 1);
    const int tid = threadIdx.x;
    const float pr = proba[be];

    if (ended[be] != 0) {
        // Ended beam: total = pr + 0 at END_TOK, -inf elsewhere.
        // Top-8 = (pr, END_TOK) then -inf at the 7 lowest indices (tie-break asc idx).
        if (tid == 0) {
            cand_v[be * 8 + 0] = pr + 0.0f;
            cand_i[be * 8 + 0] = e * Vn + END_TOK;
            const int vs[7] = {0, 1, 3, 4, 5, 6, 7};
            for (int k = 0; k < 7; ++k) {
                cand_v[be * 8 + 1 + k] = NEG_INF;
                cand_i[be * 8 + 1 + k] = e * Vn + vs[k];
            }
        }
        return;
    }

    // --- thread-local top-8 over strided float4 stream ---
    float bv[8];
    int   bi[8];
#pragma unroll
    for (int k = 0; k < 8; ++k) { bv[k] = NEG_INF; bi[k] = IDX_SENTINEL; }
    float mn = NEG_INF;        // current T-min value among slots
    int   mi = IDX_SENTINEL;   // its idx (largest idx among equal-min values)

    auto proc = [&](float val, int v) {
        // Elements arrive in ascending idx, so equal-value candidates must NOT
        // replace (reference keeps lower idx): strict > on final value.
        if (val > mn) {
            bool done = false;
#pragma unroll
            for (int k = 0; k < 8; ++k) {
                bool m = !done && (bv[k] == mn) && (bi[k] == mi);
                if (m) { bv[k] = val; bi[k] = v; }
                done = done || m;
            }
            // recompute T-min: smallest value, largest idx among ties
            mn = bv[0]; mi = bi[0];
#pragma unroll
            for (int k = 1; k < 8; ++k) {
                bool t = (bv[k] < mn) || (bv[k] == mn && bi[k] > mi);
                mn = t ? bv[k] : mn;
                mi = t ? bi[k] : mi;
            }
        }
    };

    const float4* row = (const float4*)(cp + (size_t)be * Vn);
    for (int i = tid; i < Vn / 4; i += 256) {
        float4 f = row[i];
        int v0 = i * 4;
        proc(pr + f.x, v0);
        proc(pr + f.y, v0 + 1);
        proc(pr + f.z, v0 + 2);
        proc(pr + f.w, v0 + 3);
    }

    // --- wave-level merge: 8 rounds of argmax-with-removal over 64 lanes x 8 slots ---
    const int lane = tid & 63;
    const int wid  = tid >> 6;
    __shared__ float sv[32];
    __shared__ int   si[32];

#pragma unroll
    for (int r = 0; r < 8; ++r) {
        // local T-max among remaining slots (compile-time indexing)
        float lv = bv[0]; int li = bi[0];
#pragma unroll
        for (int k = 1; k < 8; ++k) {
            bool t = (bv[k] > lv) || (bv[k] == lv && bi[k] < li);
            lv = t ? bv[k] : lv;
            li = t ? bi[k] : li;
        }
        int ll = lane;
        wave_argmax(lv, li, ll);
        if (ll == lane) {  // this lane won: consume that slot
            bool done = false;
#pragma unroll
            for (int k = 0; k < 8; ++k) {
                bool m = !done && (bi[k] == li) && (bv[k] == lv);
                if (m) { bv[k] = NEG_INF; bi[k] = IDX_SENTINEL; }
                done = done || m;
            }
        }
        if (lane == r) { sv[wid * 8 + r] = lv; si[wid * 8 + r] = li; }
    }
    __syncthreads();

    // --- block-level merge: wave 0 selects top-8 of the 4x8 wave winners ---
    if (wid == 0) {
        float cv = (lane < 32) ? sv[lane] : NEG_INF;
        int   ci = (lane < 32) ? si[lane] : IDX_SENTINEL;
#pragma unroll
        for (int r = 0; r < 8; ++r) {
            float lv = cv; int li = ci; int ll = lane;
            wave_argmax(lv, li, ll);
            if (ll == lane) { cv = NEG_INF; ci = IDX_SENTINEL; }
            if (lane == r) {
                cand_v[be * 8 + r] = lv;
                cand_i[be * 8 + r] = e * Vn + li;
            }
        }
    }
}

// Kernel 2: per-row merge of 8 segments x 8 candidates = 64, exactly one wave
// per b. Emits cur_input / top_p / ended_new / topk_beam (as fp32) and stashes
// voc/beam ints for the gather kernel.
__global__ __launch_bounds__(64) void k_merge(
        const float* __restrict__ cand_v, const int* __restrict__ cand_i,
        const int* __restrict__ ended, float* __restrict__ dout,
        int* __restrict__ sel_voc, int* __restrict__ sel_beam) {
    const int b = blockIdx.x;
    const int lane = threadIdx.x;
    float cv = cand_v[b * 64 + lane];
    int   ci = cand_i[b * 64 + lane];
    float rv = NEG_INF;
    int   rix = 0;
#pragma unroll
    for (int r = 0; r < 8; ++r) {
        float lv = cv; int li = ci; int ll = lane;
        wave_argmax(lv, li, ll);
        if (ll == lane) { cv = NEG_INF; ci = IDX_SENTINEL; }
        if (lane == r) { rv = lv; rix = li; }
    }
    if (lane < 8) {
        unsigned u = (unsigned)rix;
        int voc  = (int)(u % Vn);
        int beam = (int)(u / Vn);
        dout[OFF_CUR   + b * 8 + lane] = (float)voc;
        dout[OFF_TOPP  + b * 8 + lane] = rv;
        int endg = ended[b * 8 + beam];
        dout[OFF_ENDED + b * 8 + lane] = (endg != 0 || voc == END_TOK) ? 1.0f : 0.0f;
        dout[OFF_BEAM  + b * 8 + lane] = (float)beam;
        sel_voc[b * 8 + lane]  = voc;
        sel_beam[b * 8 + lane] = beam;
    }
}

// Kernel 3: outs_new[l,b,e] = outs[l,b,beam[b,e]] for l<L, voc[b,e] for l==L.
__global__ __launch_bounds__(256) void k_gather(
        const int* __restrict__ outs, const int* __restrict__ sel_voc,
        const int* __restrict__ sel_beam, float* __restrict__ dout) {
    int idx = blockIdx.x * 256 + threadIdx.x;
    if (idx >= (Ln + 1) * BEn) return;
    int l  = idx >> 11;          // / 2048
    int be = idx & (BEn - 1);    // % 2048
    float r;
    if (l < Ln) {
        int beam = sel_beam[be];              // sel arrays share [B][E] layout
        r = (float)outs[(l << 11) + (be & ~7) + beam];
    } else {
        r = (float)sel_voc[be];
    }
    dout[OFF_OUTS + idx] = r;
}

extern "C" void kernel_launch(void* const* d_in, const int* in_sizes, int n_in,
                              void* d_out, int out_size, void* d_ws, size_t ws_size,
                              hipStream_t stream) {
    const float* cp    = (const float*)d_in[0];  // [B*E, 1, V] fp32
    const float* proba = (const float*)d_in[1];  // [B, E] fp32
    const int*   outs  = (const int*)d_in[2];    // [L, B, E] int
    const int*   ended = (const int*)d_in[3];    // [B, E] bool->int
    float* dout = (float*)d_out;

    // workspace layout
    float* cand_v  = (float*)d_ws;                                   // 2048*8 f32
    int*   cand_i  = (int*)((char*)d_ws + BEn * 8 * sizeof(float));  // 2048*8 i32
    int*   sel_voc = (int*)((char*)d_ws + 2 * BEn * 8 * sizeof(float)); // 2048 i32
    int*   sel_beam = sel_voc + BEn;                                    // 2048 i32

    k_seg_topk<<<BEn, 256, 0, stream>>>(cp, proba, ended, cand_v, cand_i);
    k_merge<<<Bn, 64, 0, stream>>>(cand_v, cand_i, ended, dout, sel_voc, sel_beam);
    k_gather<<<((Ln + 1) * BEn + 255) / 256, 256, 0, stream>>>(outs, sel_voc, sel_beam, dout);
}

// Round 5
// 71.594 us; speedup vs baseline: 3.2859x; 3.2859x over previous
//
#include <hip/hip_runtime.h>

// Problem constants (from reference setup_inputs)
#define Bn 256
#define En 8
#define Vn 32000
#define Ln 128
#define BEn (Bn * En)        // 2048
#define END_TOK 2

// d_out layout (all values stored as float32, outputs concatenated in return order)
#define OFF_CUR   0                         // cur_input  [B*E]
#define OFF_TOPP  (BEn)                     // top_p      [B,E]
#define OFF_OUTS  (2 * BEn)                 // outs_new   [L+1,B,E]
#define OFF_ENDED (2 * BEn + (Ln + 1) * BEn) // ended_new [B,E]
#define OFF_BEAM  (3 * BEn + (Ln + 1) * BEn) // topk_beam [B,E]

#define NEG_INF (-__builtin_inff())
#define IDX_SENTINEL 0x7fffffff

// Fast-path filter threshold on RAW cp values (pr is segment-constant, fp add
// is monotone, so raw-order filtering is sound for selecting sum-order top-8
// candidates; sum-ties at the top-8 boundary lie within ~1 ulp of the 8th
// value >> 3.0, so all tie contenders pass the filter).
// 8th order statistic of 32000 N(0,1) draws ~ 3.55; P(count<8 | t=3.0) ~ 1e-9.
#define THRESH 3.0f
#define CAP    512

// Butterfly arg-max over 64 lanes under total order (val desc, idx asc).
__device__ __forceinline__ void wave_argmax(float& v, int& ix, int& ln) {
#pragma unroll
    for (int off = 32; off > 0; off >>= 1) {
        float v2 = __shfl_xor(v, off, 64);
        int   i2 = __shfl_xor(ix, off, 64);
        int   l2 = __shfl_xor(ln, off, 64);
        bool take = (v2 > v) || (v2 == v && i2 < ix);
        v  = take ? v2 : v;
        ix = take ? i2 : ix;
        ln = take ? l2 : ln;
    }
}

// Kernel 1: per-(b,e) segment top-8 of total[v] = proba[be] + cp[be][v].
// grid = BEn blocks x 256 threads.
__global__ __launch_bounds__(256) void k_seg_topk(
        const float* __restrict__ cp, const float* __restrict__ proba,
        const int* __restrict__ ended,
        float* __restrict__ cand_v, int* __restrict__ cand_i) {
    const int be = blockIdx.x;
    const int e  = be & (En - 1);
    const int tid = threadIdx.x;
    const float pr = proba[be];

    __shared__ int   s_cnt;
    __shared__ float s_cv[CAP];
    __shared__ int   s_ci[CAP];
    __shared__ float sv[32];
    __shared__ int   si[32];

    if (ended[be] != 0) {
        // Ended beam: total = pr + 0 at END_TOK, -inf elsewhere.
        if (tid == 0) {
            cand_v[be * 8 + 0] = pr + 0.0f;
            cand_i[be * 8 + 0] = e * Vn + END_TOK;
            const int vs[7] = {0, 1, 3, 4, 5, 6, 7};
            for (int k = 0; k < 7; ++k) {
                cand_v[be * 8 + 1 + k] = NEG_INF;
                cand_i[be * 8 + 1 + k] = e * Vn + vs[k];
            }
        }
        return;
    }

    if (tid == 0) s_cnt = 0;
    __syncthreads();

    // --- Phase 1: cheap streaming filter (1 cmp/elem), collect rare survivors ---
    const float4* row = (const float4*)(cp + (size_t)be * Vn);
    for (int i = tid; i < Vn / 4; i += 256) {
        float4 f = row[i];
        int v0 = i * 4;
        if (f.x > THRESH) { int p = atomicAdd(&s_cnt, 1); if (p < CAP) { s_cv[p] = f.x; s_ci[p] = v0;     } }
        if (f.y > THRESH) { int p = atomicAdd(&s_cnt, 1); if (p < CAP) { s_cv[p] = f.y; s_ci[p] = v0 + 1; } }
        if (f.z > THRESH) { int p = atomicAdd(&s_cnt, 1); if (p < CAP) { s_cv[p] = f.z; s_ci[p] = v0 + 2; } }
        if (f.w > THRESH) { int p = atomicAdd(&s_cnt, 1); if (p < CAP) { s_cv[p] = f.w; s_ci[p] = v0 + 3; } }
    }
    __syncthreads();
    const int cnt = s_cnt;   // block-uniform
    const int lane = tid & 63;
    const int wid  = tid >> 6;

    if (cnt >= 8 && cnt <= CAP) {
        // --- Fast path: exact top-8 of <=512 candidates by (pr+v desc, idx asc) ---
        float bv0 = (tid       < cnt) ? pr + s_cv[tid]       : NEG_INF;
        int   bi0 = (tid       < cnt) ? s_ci[tid]            : IDX_SENTINEL;
        float bv1 = (tid + 256 < cnt) ? pr + s_cv[tid + 256] : NEG_INF;
        int   bi1 = (tid + 256 < cnt) ? s_ci[tid + 256]      : IDX_SENTINEL;

#pragma unroll
        for (int r = 0; r < 8; ++r) {
            bool s0 = (bv0 > bv1) || (bv0 == bv1 && bi0 < bi1);
            float lv = s0 ? bv0 : bv1;
            int   li = s0 ? bi0 : bi1;
            int   ll = lane;
            wave_argmax(lv, li, ll);
            if (ll == lane) {
                if (bi0 == li && bv0 == lv) { bv0 = NEG_INF; bi0 = IDX_SENTINEL; }
                else if (bi1 == li && bv1 == lv) { bv1 = NEG_INF; bi1 = IDX_SENTINEL; }
            }
            if (lane == r) { sv[wid * 8 + r] = lv; si[wid * 8 + r] = li; }
        }
        __syncthreads();
        if (wid == 0) {
            float cv2 = (lane < 32) ? sv[lane] : NEG_INF;
            int   ci2 = (lane < 32) ? si[lane] : IDX_SENTINEL;
#pragma unroll
            for (int r = 0; r < 8; ++r) {
                float lv = cv2; int li = ci2; int ll = lane;
                wave_argmax(lv, li, ll);
                if (ll == lane) { cv2 = NEG_INF; ci2 = IDX_SENTINEL; }
                if (lane == r) {
                    cand_v[be * 8 + r] = lv;
                    cand_i[be * 8 + r] = e * Vn + li;
                }
            }
        }
        return;
    }

    // --- Fallback (provably exact, any input): per-thread top-8 + merges ---
    float bv[8];
    int   bi[8];
#pragma unroll
    for (int k = 0; k < 8; ++k) { bv[k] = NEG_INF; bi[k] = IDX_SENTINEL; }
    float mn = NEG_INF;
    int   mi = IDX_SENTINEL;

    auto proc = [&](float val, int v) {
        if (val > mn) {
            bool done = false;
#pragma unroll
            for (int k = 0; k < 8; ++k) {
                bool m = !done && (bv[k] == mn) && (bi[k] == mi);
                if (m) { bv[k] = val; bi[k] = v; }
                done = done || m;
            }
            mn = bv[0]; mi = bi[0];
#pragma unroll
            for (int k = 1; k < 8; ++k) {
                bool t = (bv[k] < mn) || (bv[k] == mn && bi[k] > mi);
                mn = t ? bv[k] : mn;
                mi = t ? bi[k] : mi;
            }
        }
    };

    for (int i = tid; i < Vn / 4; i += 256) {
        float4 f = row[i];
        int v0 = i * 4;
        proc(pr + f.x, v0);
        proc(pr + f.y, v0 + 1);
        proc(pr + f.z, v0 + 2);
        proc(pr + f.w, v0 + 3);
    }

#pragma unroll
    for (int r = 0; r < 8; ++r) {
        float lv = bv[0]; int li = bi[0];
#pragma unroll
        for (int k = 1; k < 8; ++k) {
            bool t = (bv[k] > lv) || (bv[k] == lv && bi[k] < li);
            lv = t ? bv[k] : lv;
            li = t ? bi[k] : li;
        }
        int ll = lane;
        wave_argmax(lv, li, ll);
        if (ll == lane) {
            bool done = false;
#pragma unroll
            for (int k = 0; k < 8; ++k) {
                bool m = !done && (bi[k] == li) && (bv[k] == lv);
                if (m) { bv[k] = NEG_INF; bi[k] = IDX_SENTINEL; }
                done = done || m;
            }
        }
        if (lane == r) { sv[wid * 8 + r] = lv; si[wid * 8 + r] = li; }
    }
    __syncthreads();

    if (wid == 0) {
        float cv2 = (lane < 32) ? sv[lane] : NEG_INF;
        int   ci2 = (lane < 32) ? si[lane] : IDX_SENTINEL;
#pragma unroll
        for (int r = 0; r < 8; ++r) {
            float lv = cv2; int li = ci2; int ll = lane;
            wave_argmax(lv, li, ll);
            if (ll == lane) { cv2 = NEG_INF; ci2 = IDX_SENTINEL; }
            if (lane == r) {
                cand_v[be * 8 + r] = lv;
                cand_i[be * 8 + r] = e * Vn + li;
            }
        }
    }
}

// Kernel 2: per-row merge of 8 segments x 8 candidates = 64, one wave per b.
__global__ __launch_bounds__(64) void k_merge(
        const float* __restrict__ cand_v, const int* __restrict__ cand_i,
        const int* __restrict__ ended, float* __restrict__ dout,
        int* __restrict__ sel_voc, int* __restrict__ sel_beam) {
    const int b = blockIdx.x;
    const int lane = threadIdx.x;
    float cv = cand_v[b * 64 + lane];
    int   ci = cand_i[b * 64 + lane];
    float rv = NEG_INF;
    int   rix = 0;
#pragma unroll
    for (int r = 0; r < 8; ++r) {
        float lv = cv; int li = ci; int ll = lane;
        wave_argmax(lv, li, ll);
        if (ll == lane) { cv = NEG_INF; ci = IDX_SENTINEL; }
        if (lane == r) { rv = lv; rix = li; }
    }
    if (lane < 8) {
        unsigned u = (unsigned)rix;
        int voc  = (int)(u % Vn);
        int beam = (int)(u / Vn);
        dout[OFF_CUR   + b * 8 + lane] = (float)voc;
        dout[OFF_TOPP  + b * 8 + lane] = rv;
        int endg = ended[b * 8 + beam];
        dout[OFF_ENDED + b * 8 + lane] = (endg != 0 || voc == END_TOK) ? 1.0f : 0.0f;
        dout[OFF_BEAM  + b * 8 + lane] = (float)beam;
        sel_voc[b * 8 + lane]  = voc;
        sel_beam[b * 8 + lane] = beam;
    }
}

// Kernel 3: outs_new[l,b,e] = outs[l,b,beam[b,e]] for l<L, voc[b,e] for l==L.
__global__ __launch_bounds__(256) void k_gather(
        const int* __restrict__ outs, const int* __restrict__ sel_voc,
        const int* __restrict__ sel_beam, float* __restrict__ dout) {
    int idx = blockIdx.x * 256 + threadIdx.x;
    if (idx >= (Ln + 1) * BEn) return;
    int l  = idx >> 11;          // / 2048
    int be = idx & (BEn - 1);    // % 2048
    float r;
    if (l < Ln) {
        int beam = sel_beam[be];
        r = (float)outs[(l << 11) + (be & ~7) + beam];
    } else {
        r = (float)sel_voc[be];
    }
    dout[OFF_OUTS + idx] = r;
}

extern "C" void kernel_launch(void* const* d_in, const int* in_sizes, int n_in,
                              void* d_out, int out_size, void* d_ws, size_t ws_size,
                              hipStream_t stream) {
    const float* cp    = (const float*)d_in[0];  // [B*E, 1, V] fp32
    const float* proba = (const float*)d_in[1];  // [B, E] fp32
    const int*   outs  = (const int*)d_in[2];    // [L, B, E] int
    const int*   ended = (const int*)d_in[3];    // [B, E] bool->int
    float* dout = (float*)d_out;

    float* cand_v  = (float*)d_ws;                                      // 2048*8 f32
    int*   cand_i  = (int*)((char*)d_ws + BEn * 8 * sizeof(float));     // 2048*8 i32
    int*   sel_voc = (int*)((char*)d_ws + 2 * BEn * 8 * sizeof(float)); // 2048 i32
    int*   sel_beam = sel_voc + BEn;                                    // 2048 i32

    k_seg_topk<<<BEn, 256, 0, stream>>>(cp, proba, ended, cand_v, cand_i);
    k_merge<<<Bn, 64, 0, stream>>>(cand_v, cand_i, ended, dout, sel_voc, sel_beam);
    k_gather<<<((Ln + 1) * BEn + 255) / 256, 256, 0, stream>>>(outs, sel_voc, sel_beam, dout);
}

// Round 6
// 70.690 us; speedup vs baseline: 3.3280x; 1.0128x over previous
//
#include <hip/hip_runtime.h>

// Problem constants (from reference setup_inputs)
#define Bn 256
#define En 8
#define Vn 32000
#define Ln 128
#define BEn (Bn * En)        // 2048
#define END_TOK 2

// d_out layout (all values stored as float32, outputs concatenated in return order)
#define OFF_CUR   0                          // cur_input  [B*E]
#define OFF_TOPP  (BEn)                      // top_p      [B,E]
#define OFF_OUTS  (2 * BEn)                  // outs_new   [L+1,B,E]
#define OFF_ENDED (2 * BEn + (Ln + 1) * BEn) // ended_new  [B,E]
#define OFF_BEAM  (3 * BEn + (Ln + 1) * BEn) // topk_beam  [B,E]

#define NEG_INF (-__builtin_inff())
#define IDX_SENTINEL 0x7fffffff

// Fast-path filter threshold on RAW cp values (pr is segment-constant, fp add
// is monotone, so raw-order filtering selects exactly the sum-order top-8
// candidates; boundary tie contenders are >> 3.0 and always pass).
// 8th order statistic of 32000 N(0,1) draws ~ 3.55; P(count<8 | t=3.0) ~ 1e-9.
#define THRESH 3.0f
#define CAP    512

// Butterfly arg-max over 64 lanes under total order (val desc, idx asc).
__device__ __forceinline__ void wave_argmax(float& v, int& ix, int& ln) {
#pragma unroll
    for (int off = 32; off > 0; off >>= 1) {
        float v2 = __shfl_xor(v, off, 64);
        int   i2 = __shfl_xor(ix, off, 64);
        int   l2 = __shfl_xor(ln, off, 64);
        bool take = (v2 > v) || (v2 == v && i2 < ix);
        v  = take ? v2 : v;
        ix = take ? i2 : ix;
        ln = take ? l2 : ln;
    }
}

// Kernel 1: per-(b,e) segment top-8 of total[v] = proba[be] + cp[be][v].
// grid = BEn blocks x 256 threads.
__global__ __launch_bounds__(256) void k_seg_topk(
        const float* __restrict__ cp, const float* __restrict__ proba,
        const int* __restrict__ ended,
        float* __restrict__ cand_v, int* __restrict__ cand_i) {
    const int be = blockIdx.x;
    const int e  = be & (En - 1);
    const int tid = threadIdx.x;
    const float pr = proba[be];

    __shared__ int   s_cnt;
    __shared__ float s_cv[CAP];
    __shared__ int   s_ci[CAP];
    __shared__ float sv[32];
    __shared__ int   si[32];

    if (ended[be] != 0) {
        // Ended beam: total = pr + 0 at END_TOK, -inf elsewhere.
        if (tid == 0) {
            cand_v[be * 8 + 0] = pr + 0.0f;
            cand_i[be * 8 + 0] = e * Vn + END_TOK;
            const int vs[7] = {0, 1, 3, 4, 5, 6, 7};
            for (int k = 0; k < 7; ++k) {
                cand_v[be * 8 + 1 + k] = NEG_INF;
                cand_i[be * 8 + 1 + k] = e * Vn + vs[k];
            }
        }
        return;
    }

    if (tid == 0) s_cnt = 0;
    __syncthreads();

    // --- Phase 1: streaming filter. 1 combined max-cmp per float4 (rare-taken
    // branch), two coalesced float4 streams in flight per wave. ---
    const float4* row = (const float4*)(cp + (size_t)be * Vn);

    auto check4 = [&](float4 f, int v0) {
        float m = fmaxf(fmaxf(f.x, f.y), fmaxf(f.z, f.w));
        if (m > THRESH) {
            if (f.x > THRESH) { int p = atomicAdd(&s_cnt, 1); if (p < CAP) { s_cv[p] = f.x; s_ci[p] = v0;     } }
            if (f.y > THRESH) { int p = atomicAdd(&s_cnt, 1); if (p < CAP) { s_cv[p] = f.y; s_ci[p] = v0 + 1; } }
            if (f.z > THRESH) { int p = atomicAdd(&s_cnt, 1); if (p < CAP) { s_cv[p] = f.z; s_ci[p] = v0 + 2; } }
            if (f.w > THRESH) { int p = atomicAdd(&s_cnt, 1); if (p < CAP) { s_cv[p] = f.w; s_ci[p] = v0 + 3; } }
        }
    };

    int i = tid;
    for (; i + 256 < Vn / 4; i += 512) {
        float4 f0 = row[i];
        float4 f1 = row[i + 256];
        check4(f0, i * 4);
        check4(f1, (i + 256) * 4);
    }
    if (i < Vn / 4) {
        float4 f0 = row[i];
        check4(f0, i * 4);
    }
    __syncthreads();
    const int cnt = s_cnt;   // block-uniform
    const int lane = tid & 63;
    const int wid  = tid >> 6;

    if (cnt >= 8 && cnt <= CAP) {
        // --- Fast path: exact top-8 of <=512 candidates by (pr+v desc, idx asc) ---
        float bv0 = (tid       < cnt) ? pr + s_cv[tid]       : NEG_INF;
        int   bi0 = (tid       < cnt) ? s_ci[tid]            : IDX_SENTINEL;
        float bv1 = (tid + 256 < cnt) ? pr + s_cv[tid + 256] : NEG_INF;
        int   bi1 = (tid + 256 < cnt) ? s_ci[tid + 256]      : IDX_SENTINEL;

#pragma unroll
        for (int r = 0; r < 8; ++r) {
            bool s0 = (bv0 > bv1) || (bv0 == bv1 && bi0 < bi1);
            float lv = s0 ? bv0 : bv1;
            int   li = s0 ? bi0 : bi1;
            int   ll = lane;
            wave_argmax(lv, li, ll);
            if (ll == lane) {
                if (bi0 == li && bv0 == lv) { bv0 = NEG_INF; bi0 = IDX_SENTINEL; }
                else if (bi1 == li && bv1 == lv) { bv1 = NEG_INF; bi1 = IDX_SENTINEL; }
            }
            if (lane == r) { sv[wid * 8 + r] = lv; si[wid * 8 + r] = li; }
        }
        __syncthreads();
        if (wid == 0) {
            float cv2 = (lane < 32) ? sv[lane] : NEG_INF;
            int   ci2 = (lane < 32) ? si[lane] : IDX_SENTINEL;
#pragma unroll
            for (int r = 0; r < 8; ++r) {
                float lv = cv2; int li = ci2; int ll = lane;
                wave_argmax(lv, li, ll);
                if (ll == lane) { cv2 = NEG_INF; ci2 = IDX_SENTINEL; }
                if (lane == r) {
                    cand_v[be * 8 + r] = lv;
                    cand_i[be * 8 + r] = e * Vn + li;
                }
            }
        }
        return;
    }

    // --- Fallback (provably exact, any input): per-thread top-8 + merges ---
    float bv[8];
    int   bi[8];
#pragma unroll
    for (int k = 0; k < 8; ++k) { bv[k] = NEG_INF; bi[k] = IDX_SENTINEL; }
    float mn = NEG_INF;
    int   mi = IDX_SENTINEL;

    auto proc = [&](float val, int v) {
        if (val > mn) {
            bool done = false;
#pragma unroll
            for (int k = 0; k < 8; ++k) {
                bool m = !done && (bv[k] == mn) && (bi[k] == mi);
                if (m) { bv[k] = val; bi[k] = v; }
                done = done || m;
            }
            mn = bv[0]; mi = bi[0];
#pragma unroll
            for (int k = 1; k < 8; ++k) {
                bool t = (bv[k] < mn) || (bv[k] == mn && bi[k] > mi);
                mn = t ? bv[k] : mn;
                mi = t ? bi[k] : mi;
            }
        }
    };

    for (int j = tid; j < Vn / 4; j += 256) {
        float4 f = row[j];
        int v0 = j * 4;
        proc(pr + f.x, v0);
        proc(pr + f.y, v0 + 1);
        proc(pr + f.z, v0 + 2);
        proc(pr + f.w, v0 + 3);
    }

#pragma unroll
    for (int r = 0; r < 8; ++r) {
        float lv = bv[0]; int li = bi[0];
#pragma unroll
        for (int k = 1; k < 8; ++k) {
            bool t = (bv[k] > lv) || (bv[k] == lv && bi[k] < li);
            lv = t ? bv[k] : lv;
            li = t ? bi[k] : li;
        }
        int ll = lane;
        wave_argmax(lv, li, ll);
        if (ll == lane) {
            bool done = false;
#pragma unroll
            for (int k = 0; k < 8; ++k) {
                bool m = !done && (bi[k] == li) && (bv[k] == lv);
                if (m) { bv[k] = NEG_INF; bi[k] = IDX_SENTINEL; }
                done = done || m;
            }
        }
        if (lane == r) { sv[wid * 8 + r] = lv; si[wid * 8 + r] = li; }
    }
    __syncthreads();

    if (wid == 0) {
        float cv2 = (lane < 32) ? sv[lane] : NEG_INF;
        int   ci2 = (lane < 32) ? si[lane] : IDX_SENTINEL;
#pragma unroll
        for (int r = 0; r < 8; ++r) {
            float lv = cv2; int li = ci2; int ll = lane;
            wave_argmax(lv, li, ll);
            if (ll == lane) { cv2 = NEG_INF; ci2 = IDX_SENTINEL; }
            if (lane == r) {
                cand_v[be * 8 + r] = lv;
                cand_i[be * 8 + r] = e * Vn + li;
            }
        }
    }
}

// Kernel 2 (fused merge + gather): one block per b.
// Wave 0 merges 8 segments x 8 candidates = 64 -> top-8 (exact reference
// order), writes the scalar outputs and stashes voc/beam in LDS; then the
// whole block gathers the [L+1, E] history slice.
__global__ __launch_bounds__(256) void k_merge_gather(
        const float* __restrict__ cand_v, const int* __restrict__ cand_i,
        const int* __restrict__ ended, const int* __restrict__ outs,
        float* __restrict__ dout) {
    const int b = blockIdx.x;
    const int tid = threadIdx.x;
    __shared__ int s_voc[8];
    __shared__ int s_beam[8];

    if (tid < 64) {
        const int lane = tid;
        float cv = cand_v[b * 64 + lane];
        int   ci = cand_i[b * 64 + lane];
#pragma unroll
        for (int r = 0; r < 8; ++r) {
            float lv = cv; int li = ci; int ll = lane;
            wave_argmax(lv, li, ll);
            if (ll == lane) { cv = NEG_INF; ci = IDX_SENTINEL; }
            if (lane == r) {
                unsigned u = (unsigned)li;
                int voc  = (int)(u % Vn);
                int beam = (int)(u / Vn);
                s_voc[r]  = voc;
                s_beam[r] = beam;
                dout[OFF_CUR  + b * 8 + r] = (float)voc;
                dout[OFF_TOPP + b * 8 + r] = lv;
                int endg = ended[b * 8 + beam];
                dout[OFF_ENDED + b * 8 + r] = (endg != 0 || voc == END_TOK) ? 1.0f : 0.0f;
                dout[OFF_BEAM  + b * 8 + r] = (float)beam;
            }
        }
    }
    __syncthreads();

    // gather: (L+1)*E = 1032 elements for this b
    for (int idx = tid; idx < (Ln + 1) * En; idx += 256) {
        int l = idx >> 3;
        int e = idx & 7;
        float r;
        if (l < Ln) r = (float)outs[l * BEn + b * 8 + s_beam[e]];
        else        r = (float)s_voc[e];
        dout[OFF_OUTS + l * BEn + b * 8 + e] = r;
    }
}

extern "C" void kernel_launch(void* const* d_in, const int* in_sizes, int n_in,
                              void* d_out, int out_size, void* d_ws, size_t ws_size,
                              hipStream_t stream) {
    const float* cp    = (const float*)d_in[0];  // [B*E, 1, V] fp32
    const float* proba = (const float*)d_in[1];  // [B, E] fp32
    const int*   outs  = (const int*)d_in[2];    // [L, B, E] int
    const int*   ended = (const int*)d_in[3];    // [B, E] bool->int
    float* dout = (float*)d_out;

    float* cand_v = (float*)d_ws;                                   // 2048*8 f32
    int*   cand_i = (int*)((char*)d_ws + BEn * 8 * sizeof(float));  // 2048*8 i32

    k_seg_topk<<<BEn, 256, 0, stream>>>(cp, proba, ended, cand_v, cand_i);
    k_merge_gather<<<Bn, 256, 0, stream>>>(cand_v, cand_i, ended, outs, dout);
}

// Round 7
// 68.173 us; speedup vs baseline: 3.4508x; 1.0369x over previous
//
#include <hip/hip_runtime.h>

// Problem constants (from reference setup_inputs)
#define Bn 256
#define En 8
#define Vn 32000
#define Ln 128
#define BEn (Bn * En)        // 2048
#define END_TOK 2
#define NV4 (Vn / 4)         // 8000 float4 strips per segment

// d_out layout (all values stored as float32, outputs concatenated in return order)
#define OFF_CUR   0                          // cur_input  [B*E]
#define OFF_TOPP  (BEn)                      // top_p      [B,E]
#define OFF_OUTS  (2 * BEn)                  // outs_new   [L+1,B,E]
#define OFF_ENDED (2 * BEn + (Ln + 1) * BEn) // ended_new  [B,E]
#define OFF_BEAM  (3 * BEn + (Ln + 1) * BEn) // topk_beam  [B,E]

#define NEG_INF (-__builtin_inff())
#define IDX_SENTINEL 0x7fffffff

// Fast-path filter threshold on RAW cp values (pr is segment-constant, fp add
// is monotone, so raw-order filtering selects exactly the sum-order top-8
// candidates; boundary tie contenders are >> 3.0 and always pass).
// 8th order statistic of 32000 N(0,1) draws ~ 3.55; P(count<8 | t=3.0) ~ 1e-9.
#define THRESH 3.0f
#define CAP    512

// Butterfly arg-max over 64 lanes under total order (val desc, idx asc).
__device__ __forceinline__ void wave_argmax(float& v, int& ix, int& ln) {
#pragma unroll
    for (int off = 32; off > 0; off >>= 1) {
        float v2 = __shfl_xor(v, off, 64);
        int   i2 = __shfl_xor(ix, off, 64);
        int   l2 = __shfl_xor(ln, off, 64);
        bool take = (v2 > v) || (v2 == v && i2 < ix);
        v  = take ? v2 : v;
        ix = take ? i2 : ix;
        ln = take ? l2 : ln;
    }
}

// Kernel 1: per-(b,e) segment top-8 of total[v] = proba[be] + cp[be][v].
// grid = BEn blocks x 256 threads. Filter loop keeps 4 independent float4
// streams in flight per wave (MLP=4) so the HBM queue stays fed.
__global__ __launch_bounds__(256) void k_seg_topk(
        const float* __restrict__ cp, const float* __restrict__ proba,
        const int* __restrict__ ended,
        float* __restrict__ cand_v, int* __restrict__ cand_i) {
    const int be = blockIdx.x;
    const int e  = be & (En - 1);
    const int tid = threadIdx.x;
    const float pr = proba[be];

    __shared__ int   s_cnt;
    __shared__ float s_cv[CAP];
    __shared__ int   s_ci[CAP];
    __shared__ float sv[32];
    __shared__ int   si[32];

    if (ended[be] != 0) {
        // Ended beam: total = pr + 0 at END_TOK, -inf elsewhere.
        if (tid == 0) {
            cand_v[be * 8 + 0] = pr + 0.0f;
            cand_i[be * 8 + 0] = e * Vn + END_TOK;
            const int vs[7] = {0, 1, 3, 4, 5, 6, 7};
            for (int k = 0; k < 7; ++k) {
                cand_v[be * 8 + 1 + k] = NEG_INF;
                cand_i[be * 8 + 1 + k] = e * Vn + vs[k];
            }
        }
        return;
    }

    if (tid == 0) s_cnt = 0;
    __syncthreads();

    const float4* row = (const float4*)(cp + (size_t)be * Vn);

    auto check4 = [&](float4 f, int v0) {
        float m = fmaxf(fmaxf(f.x, f.y), fmaxf(f.z, f.w));
        if (m > THRESH) {
            if (f.x > THRESH) { int p = atomicAdd(&s_cnt, 1); if (p < CAP) { s_cv[p] = f.x; s_ci[p] = v0;     } }
            if (f.y > THRESH) { int p = atomicAdd(&s_cnt, 1); if (p < CAP) { s_cv[p] = f.y; s_ci[p] = v0 + 1; } }
            if (f.z > THRESH) { int p = atomicAdd(&s_cnt, 1); if (p < CAP) { s_cv[p] = f.z; s_ci[p] = v0 + 2; } }
            if (f.w > THRESH) { int p = atomicAdd(&s_cnt, 1); if (p < CAP) { s_cv[p] = f.w; s_ci[p] = v0 + 3; } }
        }
    };

    // Main: 7 iterations x 4 independent streams (covers strips [0, 7168)).
    int i = tid;
    for (int k = 0; k < 7; ++k, i += 1024) {
        float4 f0 = row[i];
        float4 f1 = row[i + 256];
        float4 f2 = row[i + 512];
        float4 f3 = row[i + 768];
        check4(f0, i * 4);
        check4(f1, (i + 256) * 4);
        check4(f2, (i + 512) * 4);
        check4(f3, (i + 768) * 4);
    }
    // Tail: strips [7168, 7936) unconditional (3 streams), [7936, 8000) for tid<64.
    {
        float4 f0 = row[i];
        float4 f1 = row[i + 256];
        float4 f2 = row[i + 512];
        check4(f0, i * 4);
        check4(f1, (i + 256) * 4);
        check4(f2, (i + 512) * 4);
        if (i + 768 < NV4) {
            float4 f3 = row[i + 768];
            check4(f3, (i + 768) * 4);
        }
    }
    __syncthreads();
    const int cnt = s_cnt;   // block-uniform
    const int lane = tid & 63;
    const int wid  = tid >> 6;

    if (cnt >= 8 && cnt <= CAP) {
        // --- Fast path: exact top-8 of <=512 candidates by (pr+v desc, idx asc) ---
        float bv0 = (tid       < cnt) ? pr + s_cv[tid]       : NEG_INF;
        int   bi0 = (tid       < cnt) ? s_ci[tid]            : IDX_SENTINEL;
        float bv1 = (tid + 256 < cnt) ? pr + s_cv[tid + 256] : NEG_INF;
        int   bi1 = (tid + 256 < cnt) ? s_ci[tid + 256]      : IDX_SENTINEL;

#pragma unroll
        for (int r = 0; r < 8; ++r) {
            bool s0 = (bv0 > bv1) || (bv0 == bv1 && bi0 < bi1);
            float lv = s0 ? bv0 : bv1;
            int   li = s0 ? bi0 : bi1;
            int   ll = lane;
            wave_argmax(lv, li, ll);
            if (ll == lane) {
                if (bi0 == li && bv0 == lv) { bv0 = NEG_INF; bi0 = IDX_SENTINEL; }
                else if (bi1 == li && bv1 == lv) { bv1 = NEG_INF; bi1 = IDX_SENTINEL; }
            }
            if (lane == r) { sv[wid * 8 + r] = lv; si[wid * 8 + r] = li; }
        }
        __syncthreads();
        if (wid == 0) {
            float cv2 = (lane < 32) ? sv[lane] : NEG_INF;
            int   ci2 = (lane < 32) ? si[lane] : IDX_SENTINEL;
#pragma unroll
            for (int r = 0; r < 8; ++r) {
                float lv = cv2; int li = ci2; int ll = lane;
                wave_argmax(lv, li, ll);
                if (ll == lane) { cv2 = NEG_INF; ci2 = IDX_SENTINEL; }
                if (lane == r) {
                    cand_v[be * 8 + r] = lv;
                    cand_i[be * 8 + r] = e * Vn + li;
                }
            }
        }
        return;
    }

    // --- Fallback (provably exact, any input): per-thread top-8 + merges ---
    float bv[8];
    int   bi[8];
#pragma unroll
    for (int k = 0; k < 8; ++k) { bv[k] = NEG_INF; bi[k] = IDX_SENTINEL; }
    float mn = NEG_INF;
    int   mi = IDX_SENTINEL;

    auto proc = [&](float val, int v) {
        if (val > mn) {
            bool done = false;
#pragma unroll
            for (int k = 0; k < 8; ++k) {
                bool m = !done && (bv[k] == mn) && (bi[k] == mi);
                if (m) { bv[k] = val; bi[k] = v; }
                done = done || m;
            }
            mn = bv[0]; mi = bi[0];
#pragma unroll
            for (int k = 1; k < 8; ++k) {
                bool t = (bv[k] < mn) || (bv[k] == mn && bi[k] > mi);
                mn = t ? bv[k] : mn;
                mi = t ? bi[k] : mi;
            }
        }
    };

    for (int j = tid; j < NV4; j += 256) {
        float4 f = row[j];
        int v0 = j * 4;
        proc(pr + f.x, v0);
        proc(pr + f.y, v0 + 1);
        proc(pr + f.z, v0 + 2);
        proc(pr + f.w, v0 + 3);
    }

#pragma unroll
    for (int r = 0; r < 8; ++r) {
        float lv = bv[0]; int li = bi[0];
#pragma unroll
        for (int k = 1; k < 8; ++k) {
            bool t = (bv[k] > lv) || (bv[k] == lv && bi[k] < li);
            lv = t ? bv[k] : lv;
            li = t ? bi[k] : li;
        }
        int ll = lane;
        wave_argmax(lv, li, ll);
        if (ll == lane) {
            bool done = false;
#pragma unroll
            for (int k = 0; k < 8; ++k) {
                bool m = !done && (bi[k] == li) && (bv[k] == lv);
                if (m) { bv[k] = NEG_INF; bi[k] = IDX_SENTINEL; }
                done = done || m;
            }
        }
        if (lane == r) { sv[wid * 8 + r] = lv; si[wid * 8 + r] = li; }
    }
    __syncthreads();

    if (wid == 0) {
        float cv2 = (lane < 32) ? sv[lane] : NEG_INF;
        int   ci2 = (lane < 32) ? si[lane] : IDX_SENTINEL;
#pragma unroll
        for (int r = 0; r < 8; ++r) {
            float lv = cv2; int li = ci2; int ll = lane;
            wave_argmax(lv, li, ll);
            if (ll == lane) { cv2 = NEG_INF; ci2 = IDX_SENTINEL; }
            if (lane == r) {
                cand_v[be * 8 + r] = lv;
                cand_i[be * 8 + r] = e * Vn + li;
            }
        }
    }
}

// Kernel 2 (fused merge + gather): one block per b. Wave 0 merges 64 -> top-8
// (exact reference order) and writes the scalar outputs; then the whole block
// gathers the [L+1, E] history slice with 4 independent loads in flight.
__global__ __launch_bounds__(256) void k_merge_gather(
        const float* __restrict__ cand_v, const int* __restrict__ cand_i,
        const int* __restrict__ ended, const int* __restrict__ outs,
        float* __restrict__ dout) {
    const int b = blockIdx.x;
    const int tid = threadIdx.x;
    __shared__ int s_voc[8];
    __shared__ int s_beam[8];

    if (tid < 64) {
        const int lane = tid;
        float cv = cand_v[b * 64 + lane];
        int   ci = cand_i[b * 64 + lane];
#pragma unroll
        for (int r = 0; r < 8; ++r) {
            float lv = cv; int li = ci; int ll = lane;
            wave_argmax(lv, li, ll);
            if (ll == lane) { cv = NEG_INF; ci = IDX_SENTINEL; }
            if (lane == r) {
                unsigned u = (unsigned)li;
                int voc  = (int)(u % Vn);
                int beam = (int)(u / Vn);
                s_voc[r]  = voc;
                s_beam[r] = beam;
                dout[OFF_CUR  + b * 8 + r] = (float)voc;
                dout[OFF_TOPP + b * 8 + r] = lv;
                int endg = ended[b * 8 + beam];
                dout[OFF_ENDED + b * 8 + r] = (endg != 0 || voc == END_TOK) ? 1.0f : 0.0f;
                dout[OFF_BEAM  + b * 8 + r] = (float)beam;
            }
        }
    }
    __syncthreads();

    // Branch-free gather: Ln*En = 1024 = 4 x 256 exact; e and beam are
    // loop-invariant per thread, 4 loads issued before any store.
    const int e    = tid & 7;
    const int l0   = tid >> 3;
    const int bm   = s_beam[e];
    const int base = b * 8;
    int g0 = outs[(l0      ) * BEn + base + bm];
    int g1 = outs[(l0 +  32) * BEn + base + bm];
    int g2 = outs[(l0 +  64) * BEn + base + bm];
    int g3 = outs[(l0 +  96) * BEn + base + bm];
    dout[OFF_OUTS + (l0      ) * BEn + base + e] = (float)g0;
    dout[OFF_OUTS + (l0 +  32) * BEn + base + e] = (float)g1;
    dout[OFF_OUTS + (l0 +  64) * BEn + base + e] = (float)g2;
    dout[OFF_OUTS + (l0 +  96) * BEn + base + e] = (float)g3;
    if (tid < 8) dout[OFF_OUTS + Ln * BEn + base + tid] = (float)s_voc[tid];
}

extern "C" void kernel_launch(void* const* d_in, const int* in_sizes, int n_in,
                              void* d_out, int out_size, void* d_ws, size_t ws_size,
                              hipStream_t stream) {
    const float* cp    = (const float*)d_in[0];  // [B*E, 1, V] fp32
    const float* proba = (const float*)d_in[1];  // [B, E] fp32
    const int*   outs  = (const int*)d_in[2];    // [L, B, E] int
    const int*   ended = (const int*)d_in[3];    // [B, E] bool->int
    float* dout = (float*)d_out;

    float* cand_v = (float*)d_ws;                                   // 2048*8 f32
    int*   cand_i = (int*)((char*)d_ws + BEn * 8 * sizeof(float));  // 2048*8 i32

    k_seg_topk<<<BEn, 256, 0, stream>>>(cp, proba, ended, cand_v, cand_i);
    k_merge_gather<<<Bn, 256, 0, stream>>>(cand_v, cand_i, ended, outs, dout);
}